// Round 5
// baseline (83.282 us; speedup 1.0000x reference)
//
#include <hip/hip_runtime.h>

// out[i, :] = corr[i, :] * rsqrt(sum_j corr[i, j]^2)
// DIM = 8192, fp32 in / fp32 out.
//
// R4 change: deterministic partial L3 pinning. Input is exactly L3-sized
// (256 MiB); fully-temporal loads self-evict under (pseudo-)random
// replacement -> only ~50% hit rate (R3 measured FETCH = 134 MB). Instead,
// keep rows < KEEP_ROWS (13/16 = 208 MiB) temporal so they stay resident
// with 48 MiB slack, and stream the remaining 3/16 with nt loads that
// don't allocate. Stores stay nt (bypass, don't evict the pinned set).

#define DIM 8192
#define TPB 256
#define V4_PER_THREAD (DIM / (TPB * 4))  // 8
#define KEEP_ROWS 6656                   // 13/16 of 8192 -> 208 MiB pinned

typedef __attribute__((ext_vector_type(4))) float f32x4;

__global__ __launch_bounds__(TPB) void row_rescale_kernel(
    const float* __restrict__ in, float* __restrict__ out) {
  const int row = blockIdx.x;
  const f32x4* rin = reinterpret_cast<const f32x4*>(in + (size_t)row * DIM);
  f32x4* rout = reinterpret_cast<f32x4*>(out + (size_t)row * DIM);

  f32x4 v[V4_PER_THREAD];
  // Block-uniform branch: pinned rows load temporal, tail rows load nt.
  if (row < KEEP_ROWS) {
#pragma unroll
    for (int k = 0; k < V4_PER_THREAD; ++k)
      v[k] = rin[threadIdx.x + k * TPB];  // temporal: allocate in L3
  } else {
#pragma unroll
    for (int k = 0; k < V4_PER_THREAD; ++k)
      v[k] = __builtin_nontemporal_load(rin + threadIdx.x + k * TPB);
  }

  float s0 = 0.0f, s1 = 0.0f;
#pragma unroll
  for (int k = 0; k < V4_PER_THREAD; ++k) {
    if (k & 1)
      s1 += v[k].x * v[k].x + v[k].y * v[k].y + v[k].z * v[k].z + v[k].w * v[k].w;
    else
      s0 += v[k].x * v[k].x + v[k].y * v[k].y + v[k].z * v[k].z + v[k].w * v[k].w;
  }
  float s = s0 + s1;

  // Wave-level butterfly reduction (wave = 64 lanes on CDNA!).
#pragma unroll
  for (int off = 32; off > 0; off >>= 1) s += __shfl_xor(s, off, 64);

  // Cross-wave reduction: 4 waves per block.
  __shared__ float wsum[TPB / 64];
  const int lane = threadIdx.x & 63;
  const int wid = threadIdx.x >> 6;
  if (lane == 0) wsum[wid] = s;
  __syncthreads();
  const float tot = wsum[0] + wsum[1] + wsum[2] + wsum[3];
  const float inv = rsqrtf(tot);

#pragma unroll
  for (int k = 0; k < V4_PER_THREAD; ++k) {
    f32x4 o = v[k] * inv;
    __builtin_nontemporal_store(o, rout + threadIdx.x + k * TPB);  // bypass
  }
}

extern "C" void kernel_launch(void* const* d_in, const int* in_sizes, int n_in,
                              void* d_out, int out_size, void* d_ws,
                              size_t ws_size, hipStream_t stream) {
  const float* corr = (const float*)d_in[0];
  float* out = (float*)d_out;
  row_rescale_kernel<<<DIM, TPB, 0, stream>>>(corr, out);
}

// Round 6
// 82.183 us; speedup vs baseline: 1.0134x; 1.0134x over previous
//
#include <hip/hip_runtime.h>

// out[i, :] = corr[i, :] * rsqrt(sum_j corr[i, j]^2)
// DIM = 8192, fp32 in / fp32 out.
//
// One 256-thread block per row; each thread holds 32 elements (8 x f32x4)
// in registers across the reduction -> input read exactly once.
// Traffic: 268 MB read + 268 MB write (provably minimal). Memory-bound.
//
// Final configuration (R4, best of the cache-policy A/B space):
//  - TEMPORAL loads: allocate input in the 256 MiB Infinity Cache. ~50% of
//    reads hit L3 across graph replays (FETCH 134 MB measured). The hit rate
//    is capped by harness-side 1 GiB fills between replays, not by
//    self-eviction (R5 pinning probe: neutral -> falsified).
//  - NON-TEMPORAL stores: output is never re-read; nt keeps the write
//    stream from evicting the input (plain stores: 104.9 us vs 82.3 us).
// Measured: 82.3 us = 6.52 TB/s combined effective, above the 6.29 TB/s
// copy ceiling (m13); remaining headroom to write-only fill rate (~7 TB/s)
// is unreachable with 50% mandatory read traffic.

#define DIM 8192
#define TPB 256
#define V4_PER_THREAD (DIM / (TPB * 4))  // 8

typedef __attribute__((ext_vector_type(4))) float f32x4;

__global__ __launch_bounds__(TPB) void row_rescale_kernel(
    const float* __restrict__ in, float* __restrict__ out) {
  const int row = blockIdx.x;
  const f32x4* rin = reinterpret_cast<const f32x4*>(in + (size_t)row * DIM);
  f32x4* rout = reinterpret_cast<f32x4*>(out + (size_t)row * DIM);

  f32x4 v[V4_PER_THREAD];
  float s0 = 0.0f, s1 = 0.0f;
#pragma unroll
  for (int k = 0; k < V4_PER_THREAD; ++k) {
    v[k] = rin[threadIdx.x + k * TPB];  // temporal: allocate in L2/L3
    if (k & 1)
      s1 += v[k].x * v[k].x + v[k].y * v[k].y + v[k].z * v[k].z + v[k].w * v[k].w;
    else
      s0 += v[k].x * v[k].x + v[k].y * v[k].y + v[k].z * v[k].z + v[k].w * v[k].w;
  }
  float s = s0 + s1;

  // Wave-level butterfly reduction (wave = 64 lanes on CDNA!).
#pragma unroll
  for (int off = 32; off > 0; off >>= 1) s += __shfl_xor(s, off, 64);

  // Cross-wave reduction: 4 waves per block.
  __shared__ float wsum[TPB / 64];
  const int lane = threadIdx.x & 63;
  const int wid = threadIdx.x >> 6;
  if (lane == 0) wsum[wid] = s;
  __syncthreads();
  const float tot = wsum[0] + wsum[1] + wsum[2] + wsum[3];
  const float inv = rsqrtf(tot);

#pragma unroll
  for (int k = 0; k < V4_PER_THREAD; ++k) {
    f32x4 o = v[k] * inv;
    __builtin_nontemporal_store(o, rout + threadIdx.x + k * TPB);  // bypass
  }
}

extern "C" void kernel_launch(void* const* d_in, const int* in_sizes, int n_in,
                              void* d_out, int out_size, void* d_ws,
                              size_t ws_size, hipStream_t stream) {
  const float* corr = (const float*)d_in[0];
  float* out = (float*)d_out;
  row_rescale_kernel<<<DIM, TPB, 0, stream>>>(corr, out);
}